// Round 3
// baseline (11277.657 us; speedup 1.0000x reference)
//
#include <hip/hip_runtime.h>

// ---------------------------------------------------------------------------
// LSTM (L=4, B=64, T=256, H=D=1024, O=512): ONE persistent kernel, 256 WGs
// (64 per layer, 64 gate-rows each), weights held entirely in VGPRs
// (256 VGPR/lane), K-split-4 across the WG's waves, cross-cell dependencies
// via device-scope flag counters (release/acquire, agent scope), c-state in
// LDS, h 4-slot rotated in global with back-pressure. x preconverted to bf16.
// ---------------------------------------------------------------------------

typedef short           bf16x8 __attribute__((ext_vector_type(8)));
typedef unsigned short  u16x8  __attribute__((ext_vector_type(8)));
typedef float           f32x4  __attribute__((ext_vector_type(4)));

static constexpr int kB  = 64;
static constexpr int kT  = 256;
static constexpr int kH  = 1024;
static constexpr int kL  = 4;
static constexpr int kNG = 4096;   // 4*H

// ws layout (bytes)
static constexpr size_t OFF_XB   = 0;          // bf16 x          33,554,432
static constexpr size_t OFF_H    = 33554432;   // bf16 h[4][L][B][H] 2 MB
static constexpr size_t OFF_FLAG = 35651584;   // int flags[L][T]     4 KB

static __device__ __forceinline__ unsigned short f2bf(float f) {
  unsigned int u = __float_as_uint(f);
  u += 0x7fffu + ((u >> 16) & 1u);  // RNE
  return (unsigned short)(u >> 16);
}
static __device__ __forceinline__ float sigm_(float x) {
  return 1.0f / (1.0f + __expf(-x));
}
static __device__ __forceinline__ float tanh_(float x) {
  return 1.0f - 2.0f / (__expf(2.0f * x) + 1.0f);
}

__global__ __launch_bounds__(256) void prepack_x(const float* __restrict__ x,
                                                 unsigned short* __restrict__ xb) {
  size_t e = ((size_t)blockIdx.x * 256 + threadIdx.x) * 8;  // grid 8192 exact
  float4 f0 = *(const float4*)(x + e);
  float4 f1 = *(const float4*)(x + e + 4);
  u16x8 v;
  v[0] = f2bf(f0.x); v[1] = f2bf(f0.y); v[2] = f2bf(f0.z); v[3] = f2bf(f0.w);
  v[4] = f2bf(f1.x); v[5] = f2bf(f1.y); v[6] = f2bf(f1.z); v[7] = f2bf(f1.w);
  *(u16x8*)(xb + e) = v;
}

// ---------------------------------------------------------------------------
__global__ __launch_bounds__(256, 1) void lstm_persist(
    const float* __restrict__ Wih, const float* __restrict__ Whh,
    const float* __restrict__ bih, const float* __restrict__ bhh,
    const unsigned short* __restrict__ xb, unsigned short* __restrict__ hbuf,
    int* __restrict__ flags) {
  const int l    = blockIdx.x >> 6;          // layer
  const int nwg  = (blockIdx.x & 63) * 64;   // gate-row slab base
  const int tid  = threadIdx.x;
  const int lane = tid & 63;
  const int w    = tid >> 6;                 // K-split: [w*512, w*512+512)
  const int quad = lane >> 4;
  const int l15  = lane & 15;

  __shared__ float part[2][64][68];          // 34,816 B reduction buffer
  __shared__ float cst[16][66];              // c[local_unit][batch], 4,224 B

  for (int i = tid; i < 16 * 66; i += 256) (&cst[0][0])[i] = 0.0f;

  // ---- one-time: weights (fp32 -> bf16) into 256 VGPRs/lane ----
  // B-fragment: row n = nwg + nt*16 + l15 (gate-interleaved: n=4u+g),
  // k = w*512 + kc*32 + quad*8 + j. Source row r = (n&3)*1024 + (n>>2).
  bf16x8 wreg[16][4];
  {
    const float* Wsrc = (w < 2) ? Wih : Whh;
    const int kofs = (w < 2) ? w * 512 : (w - 2) * 512;
#pragma unroll
    for (int nt = 0; nt < 4; ++nt) {
      int n = nwg + nt * 16 + l15;
      int r = (n & 3) * 1024 + (n >> 2);
      const float* src = Wsrc + ((size_t)l * kNG + r) * 1024 + kofs + quad * 8;
#pragma unroll
      for (int kc = 0; kc < 16; ++kc) {
        float4 f0 = *(const float4*)(src + kc * 32);
        float4 f1 = *(const float4*)(src + kc * 32 + 4);
        bf16x8 v;
        v[0] = (short)f2bf(f0.x); v[1] = (short)f2bf(f0.y);
        v[2] = (short)f2bf(f0.z); v[3] = (short)f2bf(f0.w);
        v[4] = (short)f2bf(f1.x); v[5] = (short)f2bf(f1.y);
        v[6] = (short)f2bf(f1.z); v[7] = (short)f2bf(f1.w);
        wreg[kc][nt] = v;
      }
    }
  }

  // ---- one-time: bias for epilogue (this thread's 4 units x 4 gates) ----
  const int m_ep = (w << 4) | (lane >> 2);   // epilogue batch row
  const int ug   = lane & 3;
  float4 bs4[4];
#pragma unroll
  for (int j = 0; j < 4; ++j) {
    int u = (nwg >> 2) + 4 * j + ug;
    bs4[j].x = bih[l * kNG + u]        + bhh[l * kNG + u];
    bs4[j].y = bih[l * kNG + 1024 + u] + bhh[l * kNG + 1024 + u];
    bs4[j].z = bih[l * kNG + 2048 + u] + bhh[l * kNG + 2048 + u];
    bs4[j].w = bih[l * kNG + 3072 + u] + bhh[l * kNG + 3072 + u];
  }

  for (int t = 0; t < kT; ++t) {
    // ---- dependency waits (relaxed spin, then one acquire for cache inv) ----
    if (l > 0) {
      const int idx = (l - 1) * kT + t;
      while (__hip_atomic_load(&flags[idx], __ATOMIC_RELAXED,
                               __HIP_MEMORY_SCOPE_AGENT) < 64)
        __builtin_amdgcn_s_sleep(1);
      (void)__hip_atomic_load(&flags[idx], __ATOMIC_ACQUIRE,
                              __HIP_MEMORY_SCOPE_AGENT);
    }
    if (t > 0) {
      const int idx = l * kT + t - 1;
      while (__hip_atomic_load(&flags[idx], __ATOMIC_RELAXED,
                               __HIP_MEMORY_SCOPE_AGENT) < 64)
        __builtin_amdgcn_s_sleep(1);
      (void)__hip_atomic_load(&flags[idx], __ATOMIC_ACQUIRE,
                              __HIP_MEMORY_SCOPE_AGENT);
    }
    if (l < 3 && t >= 4) {                   // h-slot back-pressure (4 slots)
      const int idx = (l + 1) * kT + t - 4;
      while (__hip_atomic_load(&flags[idx], __ATOMIC_RELAXED,
                               __HIP_MEMORY_SCOPE_AGENT) < 64)
        __builtin_amdgcn_s_sleep(1);
      (void)__hip_atomic_load(&flags[idx], __ATOMIC_ACQUIRE,
                              __HIP_MEMORY_SCOPE_AGENT);
    }

    f32x4 acc[4][4] = {};
    const bool active = (w < 2) || (t > 0);  // w>=2 reads h_prev; zero at t=0
    if (active) {
      const unsigned short* srcA;
      size_t strideA;
      if (w < 2) {
        if (l == 0) {
          srcA = xb + (size_t)t * kH + w * 512;   // x[b][t][d], row stride T*H
          strideA = (size_t)kT * kH;
        } else {
          srcA = hbuf + (size_t)((t & 3) * kL + (l - 1)) * (kB * kH) + w * 512;
          strideA = kH;
        }
      } else {
        srcA = hbuf + (size_t)(((t - 1) & 3) * kL + l) * (kB * kH) + (w - 2) * 512;
        strideA = kH;
      }
      const unsigned short* pA[4];
#pragma unroll
      for (int i = 0; i < 4; ++i)
        pA[i] = srcA + (size_t)(i * 16 + l15) * strideA + quad * 8;

      bf16x8 abuf[4][4];                     // depth-3 prefetch ring
#pragma unroll
      for (int p = 0; p < 3; ++p)
#pragma unroll
        for (int i = 0; i < 4; ++i)
          abuf[p][i] = *(const bf16x8*)(pA[i] + p * 32);
#pragma unroll
      for (int kc = 0; kc < 16; ++kc) {
        if (kc < 13) {
#pragma unroll
          for (int i = 0; i < 4; ++i)
            abuf[(kc + 3) & 3][i] = *(const bf16x8*)(pA[i] + (kc + 3) * 32);
        }
#pragma unroll
        for (int mt = 0; mt < 4; ++mt)
#pragma unroll
          for (int nt = 0; nt < 4; ++nt)
            acc[mt][nt] = __builtin_amdgcn_mfma_f32_16x16x32_bf16(
                abuf[kc & 3][mt], wreg[kc][nt], acc[mt][nt], 0, 0, 0);
      }
    }

    // ---- K-split reduction through LDS ----
    if (w >= 2) {
      float* p = &part[w - 2][0][0];
#pragma unroll
      for (int mt = 0; mt < 4; ++mt)
#pragma unroll
        for (int nt = 0; nt < 4; ++nt)
#pragma unroll
          for (int r = 0; r < 4; ++r)
            p[(mt * 16 + quad * 4 + r) * 68 + nt * 16 + l15] = acc[mt][nt][r];
    }
    __syncthreads();
    if (w < 2) {
      float* p = &part[w][0][0];
#pragma unroll
      for (int mt = 0; mt < 4; ++mt)
#pragma unroll
        for (int nt = 0; nt < 4; ++nt)
#pragma unroll
          for (int r = 0; r < 4; ++r) {
            int a = (mt * 16 + quad * 4 + r) * 68 + nt * 16 + l15;
            p[a] += acc[mt][nt][r];
          }
    }
    __syncthreads();

    // ---- epilogue: gates -> c (LDS), h (global) ----
    unsigned short* hout = hbuf + (size_t)((t & 3) * kL + l) * (kB * kH);
#pragma unroll
    for (int j = 0; j < 4; ++j) {
      int ul = 4 * j + ug;                   // local unit 0..15
      int nb = 4 * ul;
      float4 p0 = *(const float4*)&part[0][m_ep][nb];
      float4 p1 = *(const float4*)&part[1][m_ep][nb];
      float gi = sigm_(p0.x + p1.x + bs4[j].x);
      float gf = sigm_(p0.y + p1.y + bs4[j].y);
      float gg = tanh_(p0.z + p1.z + bs4[j].z);
      float go = sigm_(p0.w + p1.w + bs4[j].w);
      float cn = gf * cst[ul][m_ep] + gi * gg;
      cst[ul][m_ep] = cn;
      hout[(size_t)m_ep * kH + (nwg >> 2) + ul] = f2bf(go * tanh_(cn));
    }

    __syncthreads();                         // drains vmcnt: h stores complete
    if (tid == 0)
      __hip_atomic_fetch_add(&flags[l * kT + t], 1, __ATOMIC_RELEASE,
                             __HIP_MEMORY_SCOPE_AGENT);
  }
}

// --- final FC: out[64,512] = h[3][t=255] @ W_fc^T + b_fc
__global__ __launch_bounds__(256) void lstm_fc(const unsigned short* __restrict__ h3,
                                               const float* __restrict__ Wfc,
                                               const float* __restrict__ bfc,
                                               float* __restrict__ out) {
  int gt = blockIdx.x * 256 + threadIdx.x;  // 32768 exact
  int b = gt >> 9, o = gt & 511;
  const unsigned short* hr = h3 + (size_t)b * kH;
  const float* wr = Wfc + (size_t)o * kH;
  float acc = bfc[o];
#pragma unroll 4
  for (int k = 0; k < kH; k += 8) {
    u16x8 hv = *(const u16x8*)(hr + k);
    float4 w0 = *(const float4*)(wr + k);
    float4 w1 = *(const float4*)(wr + k + 4);
    acc += __uint_as_float((unsigned)hv[0] << 16) * w0.x +
           __uint_as_float((unsigned)hv[1] << 16) * w0.y +
           __uint_as_float((unsigned)hv[2] << 16) * w0.z +
           __uint_as_float((unsigned)hv[3] << 16) * w0.w +
           __uint_as_float((unsigned)hv[4] << 16) * w1.x +
           __uint_as_float((unsigned)hv[5] << 16) * w1.y +
           __uint_as_float((unsigned)hv[6] << 16) * w1.z +
           __uint_as_float((unsigned)hv[7] << 16) * w1.w;
  }
  out[gt] = acc;
}

extern "C" void kernel_launch(void* const* d_in, const int* in_sizes, int n_in,
                              void* d_out, int out_size, void* d_ws, size_t ws_size,
                              hipStream_t stream) {
  (void)in_sizes; (void)n_in; (void)out_size; (void)ws_size;
  const float* x   = (const float*)d_in[0];
  const float* Wih = (const float*)d_in[1];
  const float* Whh = (const float*)d_in[2];
  const float* bih = (const float*)d_in[3];
  const float* bhh = (const float*)d_in[4];
  const float* Wfc = (const float*)d_in[5];
  const float* bfc = (const float*)d_in[6];
  float* out = (float*)d_out;

  char* ws = (char*)d_ws;
  unsigned short* xb    = (unsigned short*)(ws + OFF_XB);
  unsigned short* hbuf  = (unsigned short*)(ws + OFF_H);
  int*            flags = (int*)(ws + OFF_FLAG);

  prepack_x<<<8192, 256, 0, stream>>>(x, xb);
  hipMemsetAsync(ws + OFF_FLAG, 0, kL * kT * sizeof(int), stream);

  lstm_persist<<<256, 256, 0, stream>>>(Wih, Whh, bih, bhh, xb, hbuf, flags);

  lstm_fc<<<128, 256, 0, stream>>>(hbuf + (size_t)(3 * kL + 3) * kB * kH,
                                   Wfc, bfc, out);
}

// Round 4
// 7127.565 us; speedup vs baseline: 1.5823x; 1.5823x over previous
//
#include <hip/hip_runtime.h>

// ---------------------------------------------------------------------------
// LSTM (L=4, B=64, T=256, H=D=1024, O=512): persistent kernel, 256 WGs
// (64/layer, 64 gate-rows each), weights in VGPRs (256/lane), K-split-4.
// Handoff v2: NO acquire/release fences. Producers write h with agent-scope
// (sc0 sc1 write-through) stores + tid0 relaxed atomicAdd flag. Per XCD
// (HW_REG_XCC_ID), one elected WG copies h into a per-XCD staging buffer via
// agent loads; same-XCD WGs read it through their coherent L2 (plain loads).
// L1 staleness ruled out by capacity (2 MB distinct reads per 8-step reuse).
// ---------------------------------------------------------------------------

typedef short           bf16x8 __attribute__((ext_vector_type(8)));
typedef unsigned short  u16x8  __attribute__((ext_vector_type(8)));
typedef float           f32x4  __attribute__((ext_vector_type(4)));

static constexpr int kB  = 64;
static constexpr int kT  = 256;
static constexpr int kH  = 1024;
static constexpr int kL  = 4;
static constexpr int kNG = 4096;   // 4*H

// ws layout (bytes)
static constexpr size_t OFF_XB   = 0;           // bf16 x            33,554,432
static constexpr size_t OFF_H    = 33554432;    // bf16 h[4][L][B][H]     2 MB
static constexpr size_t OFF_STG  = 35651584;    // bf16 stg[8][4][8][64*1024] 32 MB
static constexpr size_t OFF_GF   = 69206016;    // int gf[L][T]           4 KB
static constexpr size_t OFF_TICK = 69210112;    // int tick[8][4][8]      1 KB
static constexpr size_t OFF_RDY  = 69211136;    // int rdy[8][4][8]       1 KB

static __device__ __forceinline__ unsigned short f2bf(float f) {
  unsigned int u = __float_as_uint(f);
  u += 0x7fffu + ((u >> 16) & 1u);  // RNE
  return (unsigned short)(u >> 16);
}
static __device__ __forceinline__ float sigm_(float x) {
  return 1.0f / (1.0f + __expf(-x));
}
static __device__ __forceinline__ float tanh_(float x) {
  return 1.0f - 2.0f / (__expf(2.0f * x) + 1.0f);
}
static __device__ __forceinline__ void spin_ge(int* f, int v) {
  while (__hip_atomic_load(f, __ATOMIC_RELAXED, __HIP_MEMORY_SCOPE_AGENT) < v)
    __builtin_amdgcn_s_sleep(1);
}

__global__ __launch_bounds__(256) void prepack_x(const float* __restrict__ x,
                                                 unsigned short* __restrict__ xb) {
  size_t e = ((size_t)blockIdx.x * 256 + threadIdx.x) * 8;  // grid 8192 exact
  float4 f0 = *(const float4*)(x + e);
  float4 f1 = *(const float4*)(x + e + 4);
  u16x8 v;
  v[0] = f2bf(f0.x); v[1] = f2bf(f0.y); v[2] = f2bf(f0.z); v[3] = f2bf(f0.w);
  v[4] = f2bf(f1.x); v[5] = f2bf(f1.y); v[6] = f2bf(f1.z); v[7] = f2bf(f1.w);
  *(u16x8*)(xb + e) = v;
}

// ---------------------------------------------------------------------------
__global__ __launch_bounds__(256, 1) void lstm_persist(
    const float* __restrict__ Wih, const float* __restrict__ Whh,
    const float* __restrict__ bih, const float* __restrict__ bhh,
    const unsigned short* __restrict__ xb, unsigned short* __restrict__ hbuf,
    unsigned short* __restrict__ stg, int* __restrict__ gf,
    int* __restrict__ tick, int* __restrict__ rdy) {
  const int l    = blockIdx.x >> 6;          // layer
  const int nwg  = (blockIdx.x & 63) * 64;   // gate-row slab base
  const int tid  = threadIdx.x;
  const int lane = tid & 63;
  const int w    = tid >> 6;                 // K-split: [w*512, w*512+512)
  const int quad = lane >> 4;
  const int l15  = lane & 15;

  int xcd;
  asm volatile("s_getreg_b32 %0, hwreg(HW_REG_XCC_ID)" : "=s"(xcd));
  xcd &= 7;

  __shared__ float part[2][64][68];          // 34,816 B
  __shared__ float cst[16][66];              // 4,224 B
  __shared__ int   s_w0, s_w1;

  for (int i = tid; i < 16 * 66; i += 256) (&cst[0][0])[i] = 0.0f;

  // ---- one-time: weights (fp32 -> bf16) into 256 VGPRs/lane ----
  bf16x8 wreg[16][4];
  {
    const float* Wsrc = (w < 2) ? Wih : Whh;
    const int kofs = (w < 2) ? w * 512 : (w - 2) * 512;
#pragma unroll
    for (int nt = 0; nt < 4; ++nt) {
      int n = nwg + nt * 16 + l15;
      int r = (n & 3) * 1024 + (n >> 2);     // gate-interleave: row 4u+g
      const float* src = Wsrc + ((size_t)l * kNG + r) * 1024 + kofs + quad * 8;
#pragma unroll
      for (int kc = 0; kc < 16; ++kc) {
        float4 f0 = *(const float4*)(src + kc * 32);
        float4 f1 = *(const float4*)(src + kc * 32 + 4);
        bf16x8 v;
        v[0] = (short)f2bf(f0.x); v[1] = (short)f2bf(f0.y);
        v[2] = (short)f2bf(f0.z); v[3] = (short)f2bf(f0.w);
        v[4] = (short)f2bf(f1.x); v[5] = (short)f2bf(f1.y);
        v[6] = (short)f2bf(f1.z); v[7] = (short)f2bf(f1.w);
        wreg[kc][nt] = v;
      }
    }
  }

  // ---- one-time: bias for epilogue ----
  const int m_ep = (w << 4) | (lane >> 2);
  const int ug   = lane & 3;
  float4 bs4[4];
#pragma unroll
  for (int j = 0; j < 4; ++j) {
    int u = (nwg >> 2) + 4 * j + ug;
    bs4[j].x = bih[l * kNG + u]        + bhh[l * kNG + u];
    bs4[j].y = bih[l * kNG + 1024 + u] + bhh[l * kNG + 1024 + u];
    bs4[j].z = bih[l * kNG + 2048 + u] + bhh[l * kNG + 2048 + u];
    bs4[j].w = bih[l * kNG + 3072 + u] + bhh[l * kNG + 3072 + u];
  }

  // 128 KB copy: raw h (agent loads, bypass caches) -> per-XCD staging (plain)
  auto copy128 = [&](const unsigned short* src, unsigned short* dst) {
    const unsigned long long* s = (const unsigned long long*)src;
    unsigned long long* dv = (unsigned long long*)dst;
#pragma unroll
    for (int r = 0; r < 4; ++r) {
      unsigned long long tmp[16];
#pragma unroll
      for (int i = 0; i < 16; ++i)
        tmp[i] = __hip_atomic_load(s + (size_t)(r * 16 + i) * 256 + tid,
                                   __ATOMIC_RELAXED, __HIP_MEMORY_SCOPE_AGENT);
#pragma unroll
      for (int i = 0; i < 16; ++i)
        dv[(size_t)(r * 16 + i) * 256 + tid] = tmp[i];
    }
  };
  auto stg_at = [&](int lsrc, int slot) {
    return stg + (((size_t)xcd * 4 + lsrc) * 8 + slot) * (size_t)(kB * kH);
  };

  for (int t = 0; t < kT; ++t) {
    // ---- tid0-only dependency spins + staging election ----
    if (tid == 0) {
      if (t > 0)           spin_ge(&gf[l * kT + t - 1], 64);
      if (l > 0)           spin_ge(&gf[(l - 1) * kT + t], 64);
      if (l < 3 && t >= 4) spin_ge(&gf[(l + 1) * kT + t - 4], 64);
      int w0 = 0, w1 = 0;
      if (l > 0) {
        int old = __hip_atomic_fetch_max(&tick[(xcd * 4 + (l - 1)) * 8 + (t & 7)],
                                         t + 1, __ATOMIC_RELAXED,
                                         __HIP_MEMORY_SCOPE_AGENT);
        w0 = (old < t + 1);
      }
      if (t > 0) {
        int old = __hip_atomic_fetch_max(&tick[(xcd * 4 + l) * 8 + ((t - 1) & 7)],
                                         t, __ATOMIC_RELAXED,
                                         __HIP_MEMORY_SCOPE_AGENT);
        w1 = (old < t);
      }
      s_w0 = w0; s_w1 = w1;
    }
    __syncthreads();

    // ---- elected copies: raw h -> per-XCD staging ----
    if (s_w0)
      copy128(hbuf + (size_t)((t & 3) * kL + (l - 1)) * (kB * kH),
              stg_at(l - 1, t & 7));
    if (s_w1)
      copy128(hbuf + (size_t)(((t - 1) & 3) * kL + l) * (kB * kH),
              stg_at(l, (t - 1) & 7));
    if (s_w0 | s_w1) {
      __syncthreads();  // per-wave vmcnt drain: staged data in local L2
      if (tid == 0) {
        if (s_w0)
          __hip_atomic_store(&rdy[(xcd * 4 + (l - 1)) * 8 + (t & 7)], t + 1,
                             __ATOMIC_RELAXED, __HIP_MEMORY_SCOPE_AGENT);
        if (s_w1)
          __hip_atomic_store(&rdy[(xcd * 4 + l) * 8 + ((t - 1) & 7)], t,
                             __ATOMIC_RELAXED, __HIP_MEMORY_SCOPE_AGENT);
      }
    }
    if (tid == 0) {
      if (l > 0 && !s_w0) spin_ge(&rdy[(xcd * 4 + (l - 1)) * 8 + (t & 7)], t + 1);
      if (t > 0 && !s_w1) spin_ge(&rdy[(xcd * 4 + l) * 8 + ((t - 1) & 7)], t);
    }
    __syncthreads();

    // ---- GEMM: A from staging (local L2) / xb, B from VGPRs ----
    f32x4 acc[4][4] = {};
    const bool active = (w < 2) || (t > 0);
    if (active) {
      const unsigned short* srcA;
      size_t strideA;
      if (w < 2) {
        if (l == 0) { srcA = xb + (size_t)t * kH + w * 512; strideA = (size_t)kT * kH; }
        else        { srcA = stg_at(l - 1, t & 7) + w * 512; strideA = kH; }
      } else        { srcA = stg_at(l, (t - 1) & 7) + (w - 2) * 512; strideA = kH; }
      const unsigned short* pA[4];
#pragma unroll
      for (int i = 0; i < 4; ++i)
        pA[i] = srcA + (size_t)(i * 16 + l15) * strideA + quad * 8;

      bf16x8 abuf[4][4];                     // depth-3 prefetch ring
#pragma unroll
      for (int p = 0; p < 3; ++p)
#pragma unroll
        for (int i = 0; i < 4; ++i)
          abuf[p][i] = *(const bf16x8*)(pA[i] + p * 32);
#pragma unroll
      for (int kc = 0; kc < 16; ++kc) {
        if (kc < 13) {
#pragma unroll
          for (int i = 0; i < 4; ++i)
            abuf[(kc + 3) & 3][i] = *(const bf16x8*)(pA[i] + (kc + 3) * 32);
        }
#pragma unroll
        for (int mt = 0; mt < 4; ++mt)
#pragma unroll
          for (int nt = 0; nt < 4; ++nt)
            acc[mt][nt] = __builtin_amdgcn_mfma_f32_16x16x32_bf16(
                abuf[kc & 3][mt], wreg[kc][nt], acc[mt][nt], 0, 0, 0);
      }
    }

    // ---- K-split reduction through LDS ----
    if (w >= 2) {
      float* p = &part[w - 2][0][0];
#pragma unroll
      for (int mt = 0; mt < 4; ++mt)
#pragma unroll
        for (int nt = 0; nt < 4; ++nt)
#pragma unroll
          for (int r = 0; r < 4; ++r)
            p[(mt * 16 + quad * 4 + r) * 68 + nt * 16 + l15] = acc[mt][nt][r];
    }
    __syncthreads();
    if (w < 2) {
      float* p = &part[w][0][0];
#pragma unroll
      for (int mt = 0; mt < 4; ++mt)
#pragma unroll
        for (int nt = 0; nt < 4; ++nt)
#pragma unroll
          for (int r = 0; r < 4; ++r) {
            int a = (mt * 16 + quad * 4 + r) * 68 + nt * 16 + l15;
            p[a] += acc[mt][nt][r];
          }
    }
    __syncthreads();

    // ---- epilogue: gates -> c (LDS), h (agent-scope 2B stores) ----
    unsigned short* hout = hbuf + (size_t)((t & 3) * kL + l) * (kB * kH);
#pragma unroll
    for (int j = 0; j < 4; ++j) {
      int ul = 4 * j + ug;
      int nb = 4 * ul;
      float4 p0 = *(const float4*)&part[0][m_ep][nb];
      float4 p1 = *(const float4*)&part[1][m_ep][nb];
      float gi = sigm_(p0.x + p1.x + bs4[j].x);
      float gf_ = sigm_(p0.y + p1.y + bs4[j].y);
      float gg = tanh_(p0.z + p1.z + bs4[j].z);
      float go = sigm_(p0.w + p1.w + bs4[j].w);
      float cn = gf_ * cst[ul][m_ep] + gi * gg;
      cst[ul][m_ep] = cn;
      __hip_atomic_store(&hout[(size_t)m_ep * kH + (nwg >> 2) + ul],
                         f2bf(go * tanh_(cn)), __ATOMIC_RELAXED,
                         __HIP_MEMORY_SCOPE_AGENT);
    }

    __syncthreads();  // per-wave vmcnt drain: h stores visible at fabric
    if (tid == 0)
      __hip_atomic_fetch_add(&gf[l * kT + t], 1, __ATOMIC_RELAXED,
                             __HIP_MEMORY_SCOPE_AGENT);
  }
}

// --- final FC: out[64,512] = h[3][t=255] @ W_fc^T + b_fc
__global__ __launch_bounds__(256) void lstm_fc(const unsigned short* __restrict__ h3,
                                               const float* __restrict__ Wfc,
                                               const float* __restrict__ bfc,
                                               float* __restrict__ out) {
  int gt = blockIdx.x * 256 + threadIdx.x;  // 32768 exact
  int b = gt >> 9, o = gt & 511;
  const unsigned short* hr = h3 + (size_t)b * kH;
  const float* wr = Wfc + (size_t)o * kH;
  float acc = bfc[o];
#pragma unroll 4
  for (int k = 0; k < kH; k += 8) {
    u16x8 hv = *(const u16x8*)(hr + k);
    float4 w0 = *(const float4*)(wr + k);
    float4 w1 = *(const float4*)(wr + k + 4);
    acc += __uint_as_float((unsigned)hv[0] << 16) * w0.x +
           __uint_as_float((unsigned)hv[1] << 16) * w0.y +
           __uint_as_float((unsigned)hv[2] << 16) * w0.z +
           __uint_as_float((unsigned)hv[3] << 16) * w0.w +
           __uint_as_float((unsigned)hv[4] << 16) * w1.x +
           __uint_as_float((unsigned)hv[5] << 16) * w1.y +
           __uint_as_float((unsigned)hv[6] << 16) * w1.z +
           __uint_as_float((unsigned)hv[7] << 16) * w1.w;
  }
  out[gt] = acc;
}

extern "C" void kernel_launch(void* const* d_in, const int* in_sizes, int n_in,
                              void* d_out, int out_size, void* d_ws, size_t ws_size,
                              hipStream_t stream) {
  (void)in_sizes; (void)n_in; (void)out_size; (void)ws_size;
  const float* x   = (const float*)d_in[0];
  const float* Wih = (const float*)d_in[1];
  const float* Whh = (const float*)d_in[2];
  const float* bih = (const float*)d_in[3];
  const float* bhh = (const float*)d_in[4];
  const float* Wfc = (const float*)d_in[5];
  const float* bfc = (const float*)d_in[6];
  float* out = (float*)d_out;

  char* ws = (char*)d_ws;
  unsigned short* xb   = (unsigned short*)(ws + OFF_XB);
  unsigned short* hbuf = (unsigned short*)(ws + OFF_H);
  unsigned short* stg  = (unsigned short*)(ws + OFF_STG);
  int*            gfp  = (int*)(ws + OFF_GF);
  int*            tick = (int*)(ws + OFF_TICK);
  int*            rdy  = (int*)(ws + OFF_RDY);

  prepack_x<<<8192, 256, 0, stream>>>(x, xb);
  hipMemsetAsync(ws + OFF_GF, 0, 6144, stream);  // gf + tick + rdy

  lstm_persist<<<256, 256, 0, stream>>>(Wih, Whh, bih, bhh, xb, hbuf, stg,
                                        gfp, tick, rdy);

  lstm_fc<<<128, 256, 0, stream>>>(hbuf + (size_t)(3 * kL + 3) * kB * kH,
                                   Wfc, bfc, out);
}